// Round 1
// baseline (14576.968 us; speedup 1.0000x reference)
//
#include <hip/hip_runtime.h>

static constexpr int BB = 64;      // batch
static constexpr int TT = 128;     // seq
static constexpr int EE = 300;     // embed
static constexpr int HH = 1024;    // hidden
static constexpr int OUTW = 2 * HH;

static constexpr int VK  = 1344;   // padded concat K: 1024 (h) + 300 (x) + 20 zero pad
static constexpr int KX  = HH + EE;   // 1324 real K
static constexpr int CH  = 224;    // k-chunk staged in LDS
static constexpr int NCH = VK / CH;   // 6
static constexpr int NB  = 256;    // persistent blocks (1 per CU)
static constexpr int NT  = 512;    // threads per block
static constexpr int UPB = HH / NB;   // 4 hidden units per block
static constexpr int NR  = 3 * UPB;   // 12 weight rows per block (i,g,o per unit)
static constexpr int KPW = CH / 8;    // 28 k per w-slice per chunk

// ---------- gather: embsT[s][e][b] = table[inp[b][TT-1-s]][e] (time-reversed, transposed)
__global__ __launch_bounds__(256) void k_gather(const float* __restrict__ tbl,
                                                const int* __restrict__ inp,
                                                float* __restrict__ embsT) {
  __shared__ float tile[EE * 65];   // +1 pad avoids bank conflicts on transpose
  __shared__ int toks[BB];
  const int s = blockIdx.x;
  if (threadIdx.x < BB) toks[threadIdx.x] = inp[threadIdx.x * TT + (TT - 1 - s)];
  __syncthreads();
  for (int f = threadIdx.x; f < BB * EE; f += 256) {
    int b = f / EE, e = f - b * EE;          // coalesced row reads from table
    tile[e * 65 + b] = tbl[toks[b] * EE + e];
  }
  __syncthreads();
  float* dst = embsT + s * (EE * BB);
  for (int f = threadIdx.x; f < EE * BB; f += 256) {
    int e = f >> 6, b = f & 63;              // coalesced writes
    dst[f] = tile[e * 65 + b];
  }
}

// ---------- forward direction == single cell on last token, h=c=0 (f-gate dead)
__global__ __launch_bounds__(256) void k_fwd(const float* __restrict__ Wih,
                                             const float* __restrict__ bih,
                                             const float* __restrict__ bhh,
                                             const float* __restrict__ xT,  // embsT[0]: [300][64]
                                             float* __restrict__ out) {
  const int g = blockIdx.x * 256 + threadIdx.x;  // 65536 = 1024 units * 64 batch
  const int j = g >> 6, b = g & 63;
  const float* wi = Wih + (size_t)j * EE;
  const float* wg = Wih + (size_t)(2 * HH + j) * EE;
  const float* wo = Wih + (size_t)(3 * HH + j) * EE;
  float si = 0.f, sg = 0.f, so = 0.f;
  for (int e = 0; e < EE; ++e) {
    float x = xT[e * 64 + b];                // coalesced; W reads are wave-broadcast
    si += x * wi[e];
    sg += x * wg[e];
    so += x * wo[e];
  }
  si += bih[j] + bhh[j];
  sg += bih[2 * HH + j] + bhh[2 * HH + j];
  so += bih[3 * HH + j] + bhh[3 * HH + j];
  float iv = 1.f / (1.f + expf(-si));
  float gv = tanhf(sg);
  float ov = 1.f / (1.f + expf(-so));
  out[b * OUTW + j] = ov * tanhf(iv * gv);   // c=0 -> c_new = i*g
}

// ---------- persistent backward scan: 128 steps, one device-wide sync per step
__global__ __launch_bounds__(NT, 2) void k_rec(const float* __restrict__ Whh,
                                               const float* __restrict__ Wih,
                                               const float* __restrict__ bih,
                                               const float* __restrict__ bhh,
                                               const float* __restrict__ embsT,
                                               float* __restrict__ h0buf,
                                               float* __restrict__ h1buf,
                                               unsigned int* __restrict__ syncc,
                                               float* __restrict__ out) {
  __shared__ float wc[NR * VK];    // this block's 12 rows of [Whh | Wih | 0]  (64.5 KB)
  __shared__ float vs[CH * 64];    // staged [h;x] chunk, [kk][b] layout       (57.3 KB)
  __shared__ float bias_s[NR];

  const int tid = threadIdx.x;
  const int bk  = blockIdx.x;
  const int b   = tid & 63;
  const int w   = tid >> 6;        // 0..7 : k-slice owner

  // load this block's weight rows once; reused for all 128 steps
  for (int f = tid; f < NR * VK; f += NT) {
    int r = f / VK, k = f - r * VK;
    int u = r / 3, gi = r - 3 * u;
    int j0 = bk * UPB + u;
    int row = (gi == 0) ? j0 : (gi == 1 ? 2 * HH + j0 : 3 * HH + j0);
    float v;
    if (k < HH)      v = Whh[(size_t)row * HH + k];
    else if (k < KX) v = Wih[(size_t)row * EE + (k - HH)];
    else             v = 0.f;
    wc[f] = v;
  }
  if (tid < NR) {
    int u = tid / 3, gi = tid - 3 * u;
    int j0 = bk * UPB + u;
    int row = (gi == 0) ? j0 : (gi == 1 ? 2 * HH + j0 : 3 * HH + j0);
    bias_s[tid] = bih[row] + bhh[row];
  }
  __syncthreads();

  const float* hcur = h0buf;   // zeroed by host-side memset
  float*       hnxt = h1buf;

  for (int s = 0; s < TT; ++s) {
    const float* xt = embsT + (size_t)s * (EE * BB);
    float acc[NR];
#pragma unroll
    for (int r = 0; r < NR; ++r) acc[r] = 0.f;

    for (int c = 0; c < NCH; ++c) {
      const int k0 = c * CH;
      // stage chunk: coalesced global reads, linear LDS writes
#pragma unroll
      for (int m = 0; m < (CH * 64) / NT; ++m) {   // 28 iters
        int f = tid + NT * m;
        int kk = f >> 6, b2 = f & 63;
        int k = k0 + kk;
        float v;
        if (k < HH)      v = hcur[k * 64 + b2];
        else if (k < KX) v = xt[(k - HH) * 64 + b2];
        else             v = 0.f;
        vs[f] = v;
      }
      __syncthreads();
      const int kb0 = k0 + w * KPW;
#pragma unroll
      for (int kk2 = 0; kk2 < KPW; kk2 += 4) {
        const int vb = (w * KPW + kk2) * 64 + b;
        float h0v = vs[vb];          // 2-way LDS alias across 64 lanes: free
        float h1v = vs[vb + 64];
        float h2v = vs[vb + 128];
        float h3v = vs[vb + 192];
#pragma unroll
        for (int r = 0; r < NR; ++r) {
          const float4 wv = *reinterpret_cast<const float4*>(&wc[r * VK + kb0 + kk2]);
          acc[r] = fmaf(h3v, wv.w, fmaf(h2v, wv.z, fmaf(h1v, wv.y, fmaf(h0v, wv.x, acc[r]))));
        }
      }
      __syncthreads();
    }

    // reduce the 8 k-slices, apply gates, emit h_new
    float* red = vs;                 // reuse staged-chunk LDS (24 KB needed)
#pragma unroll
    for (int r = 0; r < NR; ++r) red[(w * 64 + b) * NR + r] = acc[r];
    __syncthreads();

    if (tid < 256) {
      int u = tid >> 6;              // 0..3 ; b = tid & 63 (same b)
      float si = 0.f, sg = 0.f, so = 0.f;
#pragma unroll
      for (int w2 = 0; w2 < 8; ++w2) {
        const float* p = &red[(w2 * 64 + b) * NR + u * 3];
        si += p[0]; sg += p[1]; so += p[2];
      }
      si += bias_s[u * 3 + 0];
      sg += bias_s[u * 3 + 1];
      so += bias_s[u * 3 + 2];
      float iv = 1.f / (1.f + expf(-si));
      float gv = tanhf(sg);
      float ov = 1.f / (1.f + expf(-so));
      float hv = ov * tanhf(iv * gv);          // c stays 0 in the reference "bug"
      int j0 = bk * UPB + u;
      hnxt[j0 * 64 + b] = hv;
      if (s == TT - 1) out[b * OUTW + HH + j0] = hv;
    }

    { const float* t = hcur; hcur = hnxt; hnxt = (float*)t; }

    // device-wide barrier: release fence -> arrive -> spin -> acquire fence
    __threadfence();
    __syncthreads();
    if (tid == 0) {
      __hip_atomic_fetch_add(syncc, 1u, __ATOMIC_RELEASE, __HIP_MEMORY_SCOPE_AGENT);
      const unsigned int target = (unsigned int)(NB * (s + 1));
      while (__hip_atomic_load(syncc, __ATOMIC_RELAXED, __HIP_MEMORY_SCOPE_AGENT) < target)
        __builtin_amdgcn_s_sleep(2);
    }
    __syncthreads();
    __threadfence();                 // acquire: invalidate vL1 before reading peers' h
  }
}

extern "C" void kernel_launch(void* const* d_in, const int* in_sizes, int n_in,
                              void* d_out, int out_size, void* d_ws, size_t ws_size,
                              hipStream_t stream) {
  const float* tbl   = (const float*)d_in[0];
  const float* Wih_f = (const float*)d_in[1];
  // d_in[2] = Whh_f: dead (forward h is always 0)
  const float* bih_f = (const float*)d_in[3];
  const float* bhh_f = (const float*)d_in[4];
  const float* Wih_b = (const float*)d_in[5];
  const float* Whh_b = (const float*)d_in[6];
  const float* bih_b = (const float*)d_in[7];
  const float* bhh_b = (const float*)d_in[8];
  const int*   inp   = (const int*)d_in[9];
  float* out = (float*)d_out;

  char* ws = (char*)d_ws;
  unsigned int* syncc = (unsigned int*)ws;
  float* h0    = (float*)(ws + 1024);
  float* h1    = h0 + HH * BB;
  float* embsT = h1 + HH * BB;     // [128][300][64] f32 = 9.83 MB

  // zero the sync counter + initial h buffer (ws is poisoned 0xAA before every call)
  hipMemsetAsync(d_ws, 0, 1024 + (size_t)HH * BB * sizeof(float), stream);

  k_gather<<<dim3(TT), dim3(256), 0, stream>>>(tbl, inp, embsT);
  k_fwd<<<dim3(256), dim3(256), 0, stream>>>(Wih_f, bih_f, bhh_f, embsT, out);

  void* args[] = { (void*)&Whh_b, (void*)&Wih_b, (void*)&bih_b, (void*)&bhh_b,
                   (void*)&embsT, (void*)&h0, (void*)&h1, (void*)&syncc, (void*)&out };
  hipLaunchCooperativeKernel((void*)k_rec, dim3(NB), dim3(NT), args, 0, stream);
}